// Round 2
// baseline (248.987 us; speedup 1.0000x reference)
//
#include <hip/hip_runtime.h>

// Problem constants (B,C,H,W = 32,64,128,128)
static constexpr int Cc  = 64;
static constexpr int HWc = 16384;   // 128*128
static constexpr int Bc  = 32;

// ---------------------------------------------------------------------------
// Identity (verified): sigmoid(d)+sigmoid(-d)=1 makes A[b] = -0.5*theta, so
// out[b,n,:] = W_lin @ relu(-0.5*theta @ x[b,:,n]) + b_lin.
// Round 4: BARRIER-FREE wave-private pipeline.
//   Each wave owns a private 32-px tile stream: private x slab xp[wv], private
//   P buffer p2[wv]. All LDS RAW hazards are same-wave (DS ops in order) ->
//   NO __syncthreads in the main loop; waves drift -> memory pipe stays busy.
//   Register prefetch (8 float4) of tile t+1 issued before tile-t GEMMs.
//   W_lin lives in LDS (shared, staged once; 1 barrier total) to keep
//   VGPR <= 128 so LDS (36864 B) and VGPR both allow 4 blocks/CU = 16 waves.
// mfma_f32_16x16x32_f16 layouts (HW-verified):
//   A[m=lane&15][k=quad*8+j]  B[col=lane&15][k=quad*8+j]  D[row=quad*4+r][col=lane&15]
// GEMM1 (swapped): D1 = M1 @ x   -> lane holds P[n=lq][i=4quad+r]
// GEMM2 (swapped): D2 = W  @ P^T -> lane holds out[n=lq][c=4quad+r] -> float4 stores
// LDS strides: xp 36 dw (144 B: 16B-aligned, frag reads 2-way = free),
//   p2/w2l 72 f16 (144 B: b128 reads at minimal 8-aliasing, writes 4-way-min).
// ---------------------------------------------------------------------------

typedef _Float16 v8h __attribute__((ext_vector_type(8)));
typedef float    v4f __attribute__((ext_vector_type(4)));

union FragU { uint32_t u[4]; v8h h; };

__device__ inline uint32_t packf2(float lo, float hi) {
  union { _Float16 h[2]; uint32_t u; } r;
  r.h[0] = (_Float16)lo; r.h[1] = (_Float16)hi;
  return r.u;
}

__device__ inline v4f mfma16(v8h a, v8h b, v4f c) {
  return __builtin_amdgcn_mfma_f32_16x16x32_f16(a, b, c, 0, 0, 0);
}

// Prep: f16 weights. M1h = -0.5*theta (row-major [i][c]); Wh = W_lin ([c][i]).
__global__ void prep_weights(const float* __restrict__ theta,
                             const float* __restrict__ Wlin,
                             _Float16* __restrict__ M1h,
                             _Float16* __restrict__ Wh) {
  int t = blockIdx.x * 256 + threadIdx.x;
  if (t < Cc * Cc) {
    M1h[t] = (_Float16)(-0.5f * theta[t]);
    Wh[t]  = (_Float16)(Wlin[t]);
  }
}

__global__ __launch_bounds__(256, 4) void fused_mfma(
    const float* __restrict__ x,      // [B, C, HW]
    const _Float16* __restrict__ M1h, // [64][64]
    const _Float16* __restrict__ Wh,  // [64][64]
    const float* __restrict__ blin,   // [64]
    float* __restrict__ out)          // [B, HW, C]
{
  // All per-wave-private except w2l (read-only after the single barrier).
  __shared__ __align__(16) uint32_t xp[4][32][36];   // 18432 B: x tile, f16x2 ch-pairs
  __shared__ __align__(16) _Float16 p2[4][16][72];   //  9216 B: per-wave P scratch
  __shared__ __align__(16) _Float16 w2l[64][72];     //  9216 B: W_lin [c][i]

  const int tid  = threadIdx.x;
  const int wv   = tid >> 6;
  const int l    = tid & 63;
  const int lq   = tid & 15;
  const int quad = l >> 4;

  const int b     = blockIdx.x >> 5;                 // 32 blocks per batch
  const int npix0 = (blockIdx.x & 31) * 512 + wv * 128;
  const float* xb = x + (size_t)b * Cc * HWc + npix0;

  // ---- stage W_lin into LDS (row-major [c][i], stride 72)
  {
    const int r = tid >> 2, seg = (tid & 3) * 16;
    const uint4* wg = (const uint4*)(Wh + r * 64 + seg);
    uint4 a0 = wg[0], a1 = wg[1];
    *(uint4*)&w2l[r][seg]     = a0;
    *(uint4*)&w2l[r][seg + 8] = a1;
  }

  // ---- hoisted M1 A-frags (L2-resident) + bias
  const v8h* M1v = (const v8h*)M1h;
  v8h w1[4][2];
#pragma unroll
  for (int it = 0; it < 4; ++it)
#pragma unroll
    for (int kt = 0; kt < 2; ++kt)
      w1[it][kt] = M1v[(it * 16 + lq) * 8 + kt * 4 + quad];
  v4f bias4[4];
#pragma unroll
  for (int ct = 0; ct < 4; ++ct)
    bias4[ct] = *(const v4f*)(blin + ct * 16 + quad * 4);

  const int sp_ = l >> 3;          // staging pair-row sub-index 0..7
  const int sc  = (l & 7) * 4;     // staging col (pixels), x4

  // ---- stage tile 0 into private slab (coalesced float4, pack f16 pairs)
#pragma unroll
  for (int rep = 0; rep < 4; ++rep) {
    const int p = rep * 8 + sp_;
    const float4 e = *(const float4*)(xb + (size_t)(2 * p)     * HWc + sc);
    const float4 o = *(const float4*)(xb + (size_t)(2 * p + 1) * HWc + sc);
    uint4 w;
    w.x = packf2(e.x, o.x); w.y = packf2(e.y, o.y);
    w.z = packf2(e.z, o.z); w.w = packf2(e.w, o.w);
    *(uint4*)&xp[wv][p][sc] = w;
  }

  __syncthreads();   // the ONLY barrier: w2l visibility

#pragma unroll
  for (int t = 0; t < 4; ++t) {
    // ---- issue next tile's global loads first (latency hidden under GEMMs)
    float4 pf[8];
    if (t < 3) {
      const float* xt = xb + (t + 1) * 32;
#pragma unroll
      for (int rep = 0; rep < 4; ++rep) {
        const int p = rep * 8 + sp_;
        pf[2 * rep]     = *(const float4*)(xt + (size_t)(2 * p)     * HWc + sc);
        pf[2 * rep + 1] = *(const float4*)(xt + (size_t)(2 * p + 1) * HWc + sc);
      }
    }

    // ---- compute tile t (two 16-px column halves; p2 reused in-wave)
#pragma unroll
    for (int nt = 0; nt < 2; ++nt) {
      // x B-frags: u32 reg r = channel-pair kt*16+quad*4+r at pixel nt*16+lq
      FragU xf[2];
#pragma unroll
      for (int kt = 0; kt < 2; ++kt)
#pragma unroll
        for (int r = 0; r < 4; ++r)
          xf[kt].u[r] = xp[wv][kt * 16 + quad * 4 + r][nt * 16 + lq];

      // GEMM1: D1[i][n] = M1 @ x ; relu+pack -> p2[n=lq][i]
#pragma unroll
      for (int it = 0; it < 4; ++it) {
        v4f a = {0.f, 0.f, 0.f, 0.f};
#pragma unroll
        for (int kt = 0; kt < 2; ++kt)
          a = mfma16(w1[it][kt], xf[kt].h, a);
        uint2 w;
        w.x = packf2(fmaxf(a[0], 0.f), fmaxf(a[1], 0.f));
        w.y = packf2(fmaxf(a[2], 0.f), fmaxf(a[3], 0.f));
        *(uint2*)&p2[wv][lq][it * 16 + quad * 4] = w;
      }

      // P B-frags (in-wave lgkmcnt ordering; no barrier needed)
      FragU pr[2];
#pragma unroll
      for (int kt = 0; kt < 2; ++kt)
        pr[kt].h = *(const v8h*)&p2[wv][lq][kt * 32 + quad * 8];

      // GEMM2: D2[c][n] = W @ P^T ; lane -> out[n][4quad+r+16ct] -> float4 store
      float* orow = out + ((size_t)b * HWc + npix0 + t * 32 + nt * 16 + lq) * Cc
                    + quad * 4;
#pragma unroll
      for (int ct = 0; ct < 4; ++ct) {
        v4f a = bias4[ct];
#pragma unroll
        for (int kt = 0; kt < 2; ++kt) {
          const v8h b2 = *(const v8h*)&w2l[ct * 16 + lq][kt * 32 + quad * 8];
          a = mfma16(b2, pr[kt].h, a);
        }
        *(v4f*)(orow + ct * 16) = a;
      }
    }

    // ---- drain prefetch, pack, refill private slab (reads above precede
    //      these writes in wave program order -> safe, no barrier)
    if (t < 3) {
#pragma unroll
      for (int rep = 0; rep < 4; ++rep) {
        const int p = rep * 8 + sp_;
        uint4 w;
        w.x = packf2(pf[2 * rep].x, pf[2 * rep + 1].x);
        w.y = packf2(pf[2 * rep].y, pf[2 * rep + 1].y);
        w.z = packf2(pf[2 * rep].z, pf[2 * rep + 1].z);
        w.w = packf2(pf[2 * rep].w, pf[2 * rep + 1].w);
        *(uint4*)&xp[wv][p][sc] = w;
      }
    }
  }
}

extern "C" void kernel_launch(void* const* d_in, const int* in_sizes, int n_in,
                              void* d_out, int out_size, void* d_ws, size_t ws_size,
                              hipStream_t stream) {
  const float* x     = (const float*)d_in[0];
  const float* theta = (const float*)d_in[1];
  const float* W_lin = (const float*)d_in[2];
  const float* b_lin = (const float*)d_in[3];
  float* out = (float*)d_out;

  _Float16* M1h = (_Float16*)d_ws;
  _Float16* Wh  = M1h + Cc * Cc;

  prep_weights<<<(Cc * Cc + 255) / 256, 256, 0, stream>>>(theta, W_lin, M1h, Wh);

  const int nblocks = Bc * HWc / 512;   // 1024 blocks = 4/CU, all resident
  fused_mfma<<<nblocks, 256, 0, stream>>>(x, M1h, Wh, b_lin, out);
}